// Round 1
// baseline (244.753 us; speedup 1.0000x reference)
//
#include <hip/hip_runtime.h>

// Problem: weighted BCE over (N=4, C=3, 128^3) fp32.
//   channel c = (flat / 128^3) % 3  -> 12 contiguous slabs, slab s has c = s % 3
//   ones[c]   = count(t != 0)                 (per channel)
//   bce[c]    = -mean(t*max(log p,-100) + (1-t)*max(log1p(-p),-100))
//   weight[c] = ones>0 ? M/max(ones,1) : 1000   (M = 8,388,608 per channel)
//   out       = mean(weight*bce)
//
// Memory-bound: 201 MB read -> ~32 us floor at 6.3 TB/s.

#define THREADS 256
#define BLOCKS_PER_SLAB 128
#define NSLABS 12   // N*C = 4*3
#define NCHAN 3

__global__ __launch_bounds__(THREADS) void bce_partial(
    const float* __restrict__ input,
    const float* __restrict__ target,
    float* __restrict__ bce_sum,          // [3] accumulators
    unsigned int* __restrict__ ones_cnt,  // [3] accumulators
    long long S4)                          // float4 elements per slab
{
    const int slab = blockIdx.x / BLOCKS_PER_SLAB;
    const int blk  = blockIdx.x % BLOCKS_PER_SLAB;
    const int c    = slab % NCHAN;  // block-uniform

    const float4* __restrict__ in4 = (const float4*)input  + (long long)slab * S4;
    const float4* __restrict__ tg4 = (const float4*)target + (long long)slab * S4;

    float        lsum = 0.0f;
    unsigned int lcnt = 0u;

    const long long stride = (long long)BLOCKS_PER_SLAB * THREADS;
    for (long long i = (long long)blk * THREADS + threadIdx.x; i < S4; i += stride) {
        float4 p = in4[i];
        float4 t = tg4[i];
        float pp[4] = {p.x, p.y, p.z, p.w};
        float tt[4] = {t.x, t.y, t.z, t.w};
#pragma unroll
        for (int k = 0; k < 4; ++k) {
            float lp  = fmaxf(__logf(pp[k]),   -100.0f);
            float l1p = fmaxf(log1pf(-pp[k]),  -100.0f);
            bool  pos = (tt[k] != 0.0f);
            lsum += pos ? lp : l1p;
            lcnt += pos ? 1u : 0u;
        }
    }

    // wave (64-lane) reduction
#pragma unroll
    for (int off = 32; off > 0; off >>= 1) {
        lsum += __shfl_down(lsum, off, 64);
        lcnt += __shfl_down(lcnt, off, 64);
    }

    __shared__ float        wsum[THREADS / 64];
    __shared__ unsigned int wcnt[THREADS / 64];
    const int lane = threadIdx.x & 63;
    const int wave = threadIdx.x >> 6;
    if (lane == 0) { wsum[wave] = lsum; wcnt[wave] = lcnt; }
    __syncthreads();
    if (threadIdx.x == 0) {
        float        s = 0.0f;
        unsigned int n = 0u;
#pragma unroll
        for (int w = 0; w < THREADS / 64; ++w) { s += wsum[w]; n += wcnt[w]; }
        atomicAdd(&bce_sum[c], s);
        atomicAdd(&ones_cnt[c], n);
    }
}

__global__ void bce_final(const float* __restrict__ bce_sum,
                          const unsigned int* __restrict__ ones_cnt,
                          float* __restrict__ out,
                          float per_chan_total)
{
    if (threadIdx.x == 0 && blockIdx.x == 0) {
        float acc = 0.0f;
#pragma unroll
        for (int c = 0; c < NCHAN; ++c) {
            float ones = (float)ones_cnt[c];
            float w    = (ones > 0.0f) ? (per_chan_total / fmaxf(ones, 1.0f)) : 1000.0f;
            float bce  = -(bce_sum[c] / per_chan_total);
            acc += w * bce;
        }
        out[0] = acc / (float)NCHAN;
    }
}

extern "C" void kernel_launch(void* const* d_in, const int* in_sizes, int n_in,
                              void* d_out, int out_size, void* d_ws, size_t ws_size,
                              hipStream_t stream)
{
    const float* input  = (const float*)d_in[0];
    const float* target = (const float*)d_in[1];
    float*       out    = (float*)d_out;

    float*        bce_sum  = (float*)d_ws;
    unsigned int* ones_cnt = (unsigned int*)((char*)d_ws + NCHAN * sizeof(float));

    // zero the 6 accumulator words (ws is poisoned 0xAA before every launch)
    hipMemsetAsync(d_ws, 0, NCHAN * (sizeof(float) + sizeof(unsigned int)), stream);

    const long long total = (long long)in_sizes[0];       // 25,165,824
    const long long S4    = total / (NSLABS * 4);          // float4 per slab
    const float     M     = (float)(total / NCHAN);        // 8,388,608 per channel

    bce_partial<<<NSLABS * BLOCKS_PER_SLAB, THREADS, 0, stream>>>(
        input, target, bce_sum, ones_cnt, S4);
    bce_final<<<1, 64, 0, stream>>>(bce_sum, ones_cnt, out, M);
}

// Round 2
// 220.273 us; speedup vs baseline: 1.1111x; 1.1111x over previous
//
#include <hip/hip_runtime.h>

// Weighted BCE over (N=4, C=3, 128^3) fp32.
// Key identity (t in {0,1}): t*log(p) + (1-t)*log(1-p) = log(t ? p : 1-p)
// -> ONE v_log_f32 per element instead of __logf + log1pf polynomial.
// R0 post-mortem: log1pf libcall made the kernel VALU-bound (81% VALUBusy,
// 11.7% HBM). This version should be memory-bound (~201 MB read, ~half L3-hit).

#define THREADS 256
#define BLOCKS_PER_SLAB 128
#define NSLABS 12   // N*C = 4*3
#define NCHAN 3

__global__ __launch_bounds__(THREADS) void bce_partial(
    const float* __restrict__ input,
    const float* __restrict__ target,
    float* __restrict__ bce_sum,          // [3] accumulators
    unsigned int* __restrict__ ones_cnt,  // [3] accumulators
    long long S4)                          // float4 elements per slab
{
    const int slab = blockIdx.x / BLOCKS_PER_SLAB;
    const int blk  = blockIdx.x % BLOCKS_PER_SLAB;
    const int c    = slab % NCHAN;  // block-uniform

    const float4* __restrict__ in4 = (const float4*)input  + (long long)slab * S4;
    const float4* __restrict__ tg4 = (const float4*)target + (long long)slab * S4;

    float        lsum = 0.0f;
    unsigned int lcnt = 0u;

    const long long stride = (long long)BLOCKS_PER_SLAB * THREADS;
#pragma unroll 4
    for (long long i = (long long)blk * THREADS + threadIdx.x; i < S4; i += stride) {
        float4 p = in4[i];
        float4 t = tg4[i];
        float pp[4] = {p.x, p.y, p.z, p.w};
        float tt[4] = {t.x, t.y, t.z, t.w};
#pragma unroll
        for (int k = 0; k < 4; ++k) {
            bool  pos = (tt[k] != 0.0f);
            float x   = pos ? pp[k] : (1.0f - pp[k]);     // cndmask + sub
            lsum += fmaxf(__logf(x), -100.0f);            // one v_log_f32
            lcnt += pos ? 1u : 0u;
        }
    }

    // wave (64-lane) reduction
#pragma unroll
    for (int off = 32; off > 0; off >>= 1) {
        lsum += __shfl_down(lsum, off, 64);
        lcnt += __shfl_down(lcnt, off, 64);
    }

    __shared__ float        wsum[THREADS / 64];
    __shared__ unsigned int wcnt[THREADS / 64];
    const int lane = threadIdx.x & 63;
    const int wave = threadIdx.x >> 6;
    if (lane == 0) { wsum[wave] = lsum; wcnt[wave] = lcnt; }
    __syncthreads();
    if (threadIdx.x == 0) {
        float        s = 0.0f;
        unsigned int n = 0u;
#pragma unroll
        for (int w = 0; w < THREADS / 64; ++w) { s += wsum[w]; n += wcnt[w]; }
        atomicAdd(&bce_sum[c], s);
        atomicAdd(&ones_cnt[c], n);
    }
}

__global__ void bce_final(const float* __restrict__ bce_sum,
                          const unsigned int* __restrict__ ones_cnt,
                          float* __restrict__ out,
                          float per_chan_total)
{
    if (threadIdx.x == 0 && blockIdx.x == 0) {
        float acc = 0.0f;
#pragma unroll
        for (int c = 0; c < NCHAN; ++c) {
            float ones = (float)ones_cnt[c];
            float w    = (ones > 0.0f) ? (per_chan_total / fmaxf(ones, 1.0f)) : 1000.0f;
            float bce  = -(bce_sum[c] / per_chan_total);
            acc += w * bce;
        }
        out[0] = acc / (float)NCHAN;
    }
}

extern "C" void kernel_launch(void* const* d_in, const int* in_sizes, int n_in,
                              void* d_out, int out_size, void* d_ws, size_t ws_size,
                              hipStream_t stream)
{
    const float* input  = (const float*)d_in[0];
    const float* target = (const float*)d_in[1];
    float*       out    = (float*)d_out;

    float*        bce_sum  = (float*)d_ws;
    unsigned int* ones_cnt = (unsigned int*)((char*)d_ws + NCHAN * sizeof(float));

    // zero the 6 accumulator words (ws is poisoned 0xAA before every launch)
    hipMemsetAsync(d_ws, 0, NCHAN * (sizeof(float) + sizeof(unsigned int)), stream);

    const long long total = (long long)in_sizes[0];       // 25,165,824
    const long long S4    = total / (NSLABS * 4);          // float4 per slab
    const float     M     = (float)(total / NCHAN);        // 8,388,608 per channel

    bce_partial<<<NSLABS * BLOCKS_PER_SLAB, THREADS, 0, stream>>>(
        input, target, bce_sum, ones_cnt, S4);
    bce_final<<<1, 64, 0, stream>>>(bce_sum, ones_cnt, out, M);
}